// Round 3
// baseline (194.531 us; speedup 1.0000x reference)
//
#include <hip/hip_runtime.h>
#include <cmath>

#define BATCH 32768
#define SROW 66   // float2 stride per radix-8 row (66 mod 16 == 2 -> uniform bank pairs)

struct cplx { float x, y; };
__device__ __forceinline__ cplx cadd(cplx a, cplx b){ return {a.x+b.x, a.y+b.y}; }
__device__ __forceinline__ cplx csub(cplx a, cplx b){ return {a.x-b.x, a.y-b.y}; }
__device__ __forceinline__ cplx cmul(cplx a, cplx b){ return {a.x*b.x - a.y*b.y, a.x*b.y + a.y*b.x}; }
__device__ __forceinline__ cplx cmul_mi(cplx a){ return {a.y, -a.x}; }                 // a * (-i)
__device__ __forceinline__ cplx cmul_w81(cplx a){ const float c=0.70710678f; return {c*(a.x+a.y), c*(a.y-a.x)}; } // a*W8^1
__device__ __forceinline__ cplx cmul_w83(cplx a){ const float c=0.70710678f; return {c*(a.y-a.x), -c*(a.x+a.y)}; } // a*W8^3

// 8-point DFT, natural-order in/out: A_r = sum_m a_m * W8^{r m}
__device__ __forceinline__ void dft8(cplx a[8]) {
    cplx t0=cadd(a[0],a[4]), t4=csub(a[0],a[4]);
    cplx t1=cadd(a[1],a[5]), t5=csub(a[1],a[5]);
    cplx t2=cadd(a[2],a[6]), t6=csub(a[2],a[6]);
    cplx t3=cadd(a[3],a[7]), t7=csub(a[3],a[7]);
    cplx u0=cadd(t0,t2), u2=csub(t0,t2);
    cplx u1=cadd(t1,t3), u3=cmul_mi(csub(t1,t3));
    a[0]=cadd(u0,u1); a[4]=csub(u0,u1); a[2]=cadd(u2,u3); a[6]=csub(u2,u3);
    cplx v0=t4, v1=cmul_w81(t5), v2=cmul_mi(t6), v3=cmul_w83(t7);
    cplx w0=cadd(v0,v2), w2=csub(v0,v2);
    cplx w1=cadd(v1,v3), w3=cmul_mi(csub(v1,v3));
    a[1]=cadd(w0,w1); a[5]=csub(w0,w1); a[3]=cadd(w2,w3); a[7]=csub(w2,w3);
}

// Replicates JAX fp32 argmin(|freq - target|), first-occurrence tie-break.
__device__ __forceinline__ int nearest_bin(float fs, float target) {
    float x = target * 1024.0f / fs;
    int i0 = (int)floorf(x);
    int lo = max(0, i0 - 1), hi = min(512, i0 + 2);
    int bi = lo; float bd = 1e30f;
    for (int i = lo; i <= hi; ++i) {
        float fr = (fs * 0.5f) * ((float)i / 512.0f);
        float d = fabsf(fr - target);
        if (d < bd) { bd = d; bi = i; }
    }
    return bi;
}

// One wave per row. 512-pt complex FFT of packed even/odd samples (radix 8x8x8,
// register DFT-8s, two b64 LDS transposes), rfft combine via cross-lane shuffles.
__global__ __launch_bounds__(256) void fft_loss_kernel(
    const float* __restrict__ preds, const float* __restrict__ Fs,
    float* __restrict__ blockpartial)
{
    __shared__ float2 lds[4][8 * SROW];   // 16896 B
    __shared__ float sblk[4];

    const int tid  = threadIdx.x;
    const int wv   = tid >> 6;
    const int lane = tid & 63;
    const int row  = blockIdx.x * 4 + wv;

    float2* sm = lds[wv];
    const float2* x2 = reinterpret_cast<const float2*>(preds) + (size_t)row * 512;

    // ---- Stage A: lane = n0; DFT8 over n1 (stride-64) ----
    cplx z[8];
#pragma unroll
    for (int n1 = 0; n1 < 8; ++n1) {
        float2 v = x2[n1 * 64 + lane];
        z[n1] = {v.x, v.y};
    }
    dft8(z);
    {   // W_512^{r*n0} via recurrence
        float sb, cb;
        __sincosf(-0.012271846f * (float)lane, &sb, &cb);
        cplx w = {cb, sb}, u = w;
#pragma unroll
        for (int r = 1; r < 8; ++r) { z[r] = cmul(z[r], u); u = cmul(u, w); }
    }
#pragma unroll
    for (int r = 0; r < 8; ++r) sm[r * SROW + lane] = make_float2(z[r].x, z[r].y);

    // ---- Stage B: lane = (r, m0); DFT8 over m1 ----
    const int rB = lane & 7, m0 = lane >> 3;
    cplx b[8];
#pragma unroll
    for (int m1 = 0; m1 < 8; ++m1) {
        float2 v = sm[rB * SROW + 8 * m1 + m0];
        b[m1] = {v.x, v.y};
    }
    dft8(b);
    {   // W_64^{s*m0}
        float sb, cb;
        __sincosf(-0.09817477f * (float)m0, &sb, &cb);
        cplx w = {cb, sb}, u = w;
#pragma unroll
        for (int s = 1; s < 8; ++s) { b[s] = cmul(b[s], u); u = cmul(u, w); }
    }
#pragma unroll
    for (int s = 0; s < 8; ++s) {   // XOR-swizzled 8x8 transpose
        sm[rB * SROW + 8 * m0 + ((s + m0) & 7)] = make_float2(b[s].x, b[s].y);
    }

    // ---- Stage C: lane = (r, s); DFT8 over m0 -> c[t] = Z[lane + 64 t] ----
    const int sC = lane >> 3;
    cplx c[8];
#pragma unroll
    for (int m = 0; m < 8; ++m) {
        float2 v = sm[rB * SROW + 8 * m + ((sC + m) & 7)];
        c[m] = {v.x, v.y};
    }
    dft8(c);

    // ---- rfft combine via shuffles: X[k] = E + W_1024^k * O ----
    const float fs  = Fs[row];
    const int left  = nearest_bin(fs, (float)(40.0 / 60.0));
    const int right = nearest_bin(fs, 3.0f);
    const int pl    = (64 - lane) & 63;     // partner lane for k2 = (512-k)&511

    float psd[8];
    float total = 0.f, inb = 0.f, best = -1.f;
    int besti = 1 << 30;
    float sk, ck;
    __sincosf(-0.0061359233f * (float)lane, &sk, &ck);
    cplx wk = {ck, sk};
    const cplx wstep = {0.92387953f, -0.38268343f};    // W_1024^64
#pragma unroll
    for (int t = 0; t < 8; ++t) {
        cplx a = c[t];
        float px = __shfl(c[7 - t].x, pl);
        float py = __shfl(c[7 - t].y, pl);
        if (lane == 0) { px = c[(8 - t) & 7].x; py = c[(8 - t) & 7].y; }
        // bb = conj(Z[k2])
        float ex = 0.5f * (a.x + px), ey = 0.5f * (a.y - py);
        float dx = a.x - px,          dy = a.y + py;
        float ox = 0.5f * dy,         oy = -0.5f * dx;
        float Xr = ex + wk.x * ox - wk.y * oy;
        float Xi = ey + wk.x * oy + wk.y * ox;
        float v  = Xr * Xr + Xi * Xi;
        psd[t] = v;
        total += v;
        int k = lane + 64 * t;
        if (k >= left && k < right) {
            inb += v;
            if (v > best) { best = v; besti = k; }
        }
        wk = cmul(wk, wstep);
    }
    if (lane == 0) {    // Nyquist bin k=512: X = Z[0].x - Z[0].y (never in band)
        float d = c[0].x - c[0].y;
        total += d * d;
    }

    // ---- wave reduce: sums + argmax (min-index tie-break) ----
#pragma unroll
    for (int off = 32; off > 0; off >>= 1) {
        total += __shfl_down(total, off);
        inb   += __shfl_down(inb, off);
        float ob = __shfl_down(best, off);
        int   oi = __shfl_down(besti, off);
        if (ob > best || (ob == best && oi < besti)) { best = ob; besti = oi; }
    }
    // peak window sum, register-resident
    const int bbi = __shfl(besti, 0);
    int delta = (int)rintf(0.1f / ((fs * 0.5f) / 513.0f));
    if (delta < 1) delta = 1;
    const int lo = max(left, bbi - delta), hi = min(right, bbi + delta);
    float wsum = 0.f;
#pragma unroll
    for (int t = 0; t < 8; ++t) {
        int k = lane + 64 * t;
        if (k >= lo && k < hi) wsum += psd[t];
    }
#pragma unroll
    for (int off = 32; off > 0; off >>= 1) wsum += __shfl_down(wsum, off);

    if (lane == 0) {
        float band = (total - inb) / (1e-8f + total);
        float den  = inb + 1e-8f * (float)(right - left);
        sblk[wv] = band + (inb - wsum) / den;
    }
    __syncthreads();
    if (tid == 0) blockpartial[blockIdx.x] = sblk[0] + sblk[1] + sblk[2] + sblk[3];
}

__global__ __launch_bounds__(1024) void reduce_kernel(
    const float* __restrict__ bp, float* __restrict__ out)
{
    __shared__ float w[16];
    const int t = threadIdx.x;
    float acc = 0.f;
#pragma unroll
    for (int i = 0; i < 8; ++i) acc += bp[t + 1024 * i];
    for (int off = 32; off > 0; off >>= 1) acc += __shfl_down(acc, off);
    const int lane = t & 63, wvi = t >> 6;
    if (lane == 0) w[wvi] = acc;
    __syncthreads();
    if (t == 0) {
        float s = 0.f;
        for (int i = 0; i < 16; ++i) s += w[i];
        out[0] = s * (1.0f / (float)BATCH);
    }
}

extern "C" void kernel_launch(void* const* d_in, const int* in_sizes, int n_in,
                              void* d_out, int out_size, void* d_ws, size_t ws_size,
                              hipStream_t stream) {
    const float* preds = (const float*)d_in[0];
    const float* Fs    = (const float*)d_in[1];
    float* bp          = (float*)d_ws;      // 8192 floats = 32 KB
    float* out         = (float*)d_out;

    fft_loss_kernel<<<BATCH / 4, 256, 0, stream>>>(preds, Fs, bp);
    reduce_kernel<<<1, 1024, 0, stream>>>(bp, out);
}

// Round 4
// 193.606 us; speedup vs baseline: 1.0048x; 1.0048x over previous
//
#include <hip/hip_runtime.h>
#include <cmath>

#define BATCH 32768
#define SROW 66   // float2 stride per radix-8 row (66 mod 16 == 2 -> uniform bank pairs)

struct cplx { float x, y; };
__device__ __forceinline__ cplx cadd(cplx a, cplx b){ return {a.x+b.x, a.y+b.y}; }
__device__ __forceinline__ cplx csub(cplx a, cplx b){ return {a.x-b.x, a.y-b.y}; }
__device__ __forceinline__ cplx cmul(cplx a, cplx b){ return {a.x*b.x - a.y*b.y, a.x*b.y + a.y*b.x}; }
__device__ __forceinline__ cplx cmul_mi(cplx a){ return {a.y, -a.x}; }                 // a * (-i)
__device__ __forceinline__ cplx cmul_w81(cplx a){ const float c=0.70710678f; return {c*(a.x+a.y), c*(a.y-a.x)}; } // a*W8^1
__device__ __forceinline__ cplx cmul_w83(cplx a){ const float c=0.70710678f; return {c*(a.y-a.x), -c*(a.x+a.y)}; } // a*W8^3

// 8-point DFT, natural-order in/out: A_r = sum_m a_m * W8^{r m}
__device__ __forceinline__ void dft8(cplx a[8]) {
    cplx t0=cadd(a[0],a[4]), t4=csub(a[0],a[4]);
    cplx t1=cadd(a[1],a[5]), t5=csub(a[1],a[5]);
    cplx t2=cadd(a[2],a[6]), t6=csub(a[2],a[6]);
    cplx t3=cadd(a[3],a[7]), t7=csub(a[3],a[7]);
    cplx u0=cadd(t0,t2), u2=csub(t0,t2);
    cplx u1=cadd(t1,t3), u3=cmul_mi(csub(t1,t3));
    a[0]=cadd(u0,u1); a[4]=csub(u0,u1); a[2]=cadd(u2,u3); a[6]=csub(u2,u3);
    cplx v0=t4, v1=cmul_w81(t5), v2=cmul_mi(t6), v3=cmul_w83(t7);
    cplx w0=cadd(v0,v2), w2=csub(v0,v2);
    cplx w1=cadd(v1,v3), w3=cmul_mi(csub(v1,v3));
    a[1]=cadd(w0,w1); a[5]=csub(w0,w1); a[3]=cadd(w2,w3); a[7]=csub(w2,w3);
}

// Replicates JAX fp32 argmin(|freq - target|), first-occurrence tie-break.
__device__ __forceinline__ int nearest_bin(float fs, float target) {
    float x = target * 1024.0f / fs;
    int i0 = (int)floorf(x);
    int lo = max(0, i0 - 1), hi = min(512, i0 + 2);
    int bi = lo; float bd = 1e30f;
    for (int i = lo; i <= hi; ++i) {
        float fr = (fs * 0.5f) * ((float)i / 512.0f);
        float d = fabsf(fr - target);
        if (d < bd) { bd = d; bi = i; }
    }
    return bi;
}

// One wave per TWO rows (stage-interleaved for ILP). Per row: 512-pt complex FFT
// of packed even/odd samples (radix 8x8x8, register DFT-8s, two b64 LDS
// transposes), rfft combine via cross-lane shuffles.
__global__ __launch_bounds__(256, 4) void fft_loss_kernel(
    const float* __restrict__ preds, const float* __restrict__ Fs,
    float* __restrict__ blockpartial)
{
    __shared__ float2 lds[4][2][8 * SROW];   // 33792 B
    __shared__ float sblk[4];

    const int tid  = threadIdx.x;
    const int wv   = tid >> 6;
    const int lane = tid & 63;
    const int row0 = blockIdx.x * 8 + wv * 2;

    const float2* x2 = reinterpret_cast<const float2*>(preds) + (size_t)row0 * 512;

    // ---- Loads: both rows up front (16 independent dwordx2) ----
    cplx z[2][8];
#pragma unroll
    for (int rr = 0; rr < 2; ++rr)
#pragma unroll
        for (int n1 = 0; n1 < 8; ++n1) {
            float2 v = x2[rr * 512 + n1 * 64 + lane];
            z[rr][n1] = {v.x, v.y};
        }

    // ---- Stage A: lane = n0; DFT8 over n1 (stride-64) ----
    {
        float sb, cb;
        __sincosf(-0.012271846f * (float)lane, &sb, &cb);   // -2pi/512 * lane
        cplx wA = {cb, sb};
#pragma unroll
        for (int rr = 0; rr < 2; ++rr) {
            dft8(z[rr]);
            cplx u = wA;
#pragma unroll
            for (int r = 1; r < 8; ++r) { z[rr][r] = cmul(z[rr][r], u); u = cmul(u, wA); }
#pragma unroll
            for (int r = 0; r < 8; ++r)
                lds[wv][rr][r * SROW + lane] = make_float2(z[rr][r].x, z[rr][r].y);
        }
    }

    // ---- Stage B: lane = (r, m0); DFT8 over m1 ----
    const int rB = lane & 7, m0 = lane >> 3;
    {
        float sb, cb;
        __sincosf(-0.09817477f * (float)m0, &sb, &cb);      // -2pi/64 * m0
        cplx wB = {cb, sb};
#pragma unroll
        for (int rr = 0; rr < 2; ++rr) {
#pragma unroll
            for (int m1 = 0; m1 < 8; ++m1) {
                float2 v = lds[wv][rr][rB * SROW + 8 * m1 + m0];
                z[rr][m1] = {v.x, v.y};
            }
            dft8(z[rr]);
            cplx u = wB;
#pragma unroll
            for (int s = 1; s < 8; ++s) { z[rr][s] = cmul(z[rr][s], u); u = cmul(u, wB); }
#pragma unroll
            for (int s = 0; s < 8; ++s)     // XOR-swizzled 8x8 transpose
                lds[wv][rr][rB * SROW + 8 * m0 + ((s + m0) & 7)] = make_float2(z[rr][s].x, z[rr][s].y);
        }
    }

    // ---- Stage C: lane = (r, s); DFT8 over m0 -> z[rr][t] = Z[lane + 64 t] ----
    const int sC = lane >> 3;
#pragma unroll
    for (int rr = 0; rr < 2; ++rr) {
#pragma unroll
        for (int m = 0; m < 8; ++m) {
            float2 v = lds[wv][rr][rB * SROW + 8 * m + ((sC + m) & 7)];
            z[rr][m] = {v.x, v.y};
        }
        dft8(z[rr]);
    }

    // ---- rfft combine via shuffles: X[k] = E + W_1024^k * O ----
    const float fsA = Fs[row0], fsB = Fs[row0 + 1];
    const float fs_[2] = {fsA, fsB};
    const int pl = (64 - lane) & 63;        // partner lane for k2 = (512-k)&511

    float wk0x, wk0y;
    {
        float sk, ck;
        __sincosf(-0.0061359233f * (float)lane, &sk, &ck);  // -2pi/1024 * lane
        wk0x = ck; wk0y = sk;
    }
    const cplx wstep = {0.92387953f, -0.38268343f};         // W_1024^64

    float psd[2][8];
    float total[2] = {0.f, 0.f}, inb[2] = {0.f, 0.f}, best[2] = {-1.f, -1.f};
    int besti[2] = {1 << 30, 1 << 30};
    int left_[2], right_[2];
#pragma unroll
    for (int rr = 0; rr < 2; ++rr) {
        left_[rr]  = nearest_bin(fs_[rr], (float)(40.0 / 60.0));
        right_[rr] = nearest_bin(fs_[rr], 3.0f);
        cplx wk = {wk0x, wk0y};
#pragma unroll
        for (int t = 0; t < 8; ++t) {
            cplx a = z[rr][t];
            float px = __shfl(z[rr][7 - t].x, pl);
            float py = __shfl(z[rr][7 - t].y, pl);
            if (lane == 0) { px = z[rr][(8 - t) & 7].x; py = z[rr][(8 - t) & 7].y; }
            float ex = 0.5f * (a.x + px), ey = 0.5f * (a.y - py);
            float dx = a.x - px,          dy = a.y + py;
            float ox = 0.5f * dy,         oy = -0.5f * dx;
            float Xr = ex + wk.x * ox - wk.y * oy;
            float Xi = ey + wk.x * oy + wk.y * ox;
            float v  = Xr * Xr + Xi * Xi;
            psd[rr][t] = v;
            total[rr] += v;
            int k = lane + 64 * t;
            if (k >= left_[rr] && k < right_[rr]) {
                inb[rr] += v;
                if (v > best[rr]) { best[rr] = v; besti[rr] = k; }
            }
            wk = cmul(wk, wstep);
        }
        if (lane == 0) {    // Nyquist bin k=512 (never in band)
            float d = z[rr][0].x - z[rr][0].y;
            total[rr] += d * d;
        }
    }

    // ---- wave reduce: sums + argmax (min-index tie-break), both rows interleaved ----
#pragma unroll
    for (int off = 32; off > 0; off >>= 1) {
#pragma unroll
        for (int rr = 0; rr < 2; ++rr) {
            total[rr] += __shfl_down(total[rr], off);
            inb[rr]   += __shfl_down(inb[rr], off);
            float ob = __shfl_down(best[rr], off);
            int   oi = __shfl_down(besti[rr], off);
            if (ob > best[rr] || (ob == best[rr] && oi < besti[rr])) { best[rr] = ob; besti[rr] = oi; }
        }
    }
    // peak window sums, register-resident
    float wsum[2] = {0.f, 0.f};
#pragma unroll
    for (int rr = 0; rr < 2; ++rr) {
        const int bbi = __shfl(besti[rr], 0);
        int delta = (int)rintf(0.1f / ((fs_[rr] * 0.5f) / 513.0f));
        if (delta < 1) delta = 1;
        const int lo = max(left_[rr], bbi - delta), hi = min(right_[rr], bbi + delta);
#pragma unroll
        for (int t = 0; t < 8; ++t) {
            int k = lane + 64 * t;
            if (k >= lo && k < hi) wsum[rr] += psd[rr][t];
        }
    }
#pragma unroll
    for (int off = 32; off > 0; off >>= 1) {
        wsum[0] += __shfl_down(wsum[0], off);
        wsum[1] += __shfl_down(wsum[1], off);
    }

    if (lane == 0) {
        float acc = 0.f;
#pragma unroll
        for (int rr = 0; rr < 2; ++rr) {
            float band = (total[rr] - inb[rr]) / (1e-8f + total[rr]);
            float den  = inb[rr] + 1e-8f * (float)(right_[rr] - left_[rr]);
            acc += band + (inb[rr] - wsum[rr]) / den;
        }
        sblk[wv] = acc;
    }
    __syncthreads();
    if (tid == 0) blockpartial[blockIdx.x] = sblk[0] + sblk[1] + sblk[2] + sblk[3];
}

__global__ __launch_bounds__(1024) void reduce_kernel(
    const float* __restrict__ bp, float* __restrict__ out)
{
    __shared__ float w[16];
    const int t = threadIdx.x;
    float acc = 0.f;
#pragma unroll
    for (int i = 0; i < 4; ++i) acc += bp[t + 1024 * i];
    for (int off = 32; off > 0; off >>= 1) acc += __shfl_down(acc, off);
    const int lane = t & 63, wvi = t >> 6;
    if (lane == 0) w[wvi] = acc;
    __syncthreads();
    if (t == 0) {
        float s = 0.f;
        for (int i = 0; i < 16; ++i) s += w[i];
        out[0] = s * (1.0f / (float)BATCH);
    }
}

extern "C" void kernel_launch(void* const* d_in, const int* in_sizes, int n_in,
                              void* d_out, int out_size, void* d_ws, size_t ws_size,
                              hipStream_t stream) {
    const float* preds = (const float*)d_in[0];
    const float* Fs    = (const float*)d_in[1];
    float* bp          = (float*)d_ws;      // 4096 floats = 16 KB
    float* out         = (float*)d_out;

    fft_loss_kernel<<<BATCH / 8, 256, 0, stream>>>(preds, Fs, bp);
    reduce_kernel<<<1, 1024, 0, stream>>>(bp, out);
}